// Round 3
// baseline (3065.154 us; speedup 1.0000x reference)
//
#include <hip/hip_runtime.h>
#include <math.h>

#define TPB 256
#define SC_TPB 256
#define SC_ITEMS 8   // 2048 elements per scan block

// ---------------- normalization + degree/count ----------------

__global__ void k_init(float* __restrict__ deg, int* __restrict__ cnt, int n) {
    int i = blockIdx.x * blockDim.x + threadIdx.x;
    if (i < n) { deg[i] = 1.0f; cnt[i] = 0; }  // self-loop weight = 1
}

__global__ void k_deg_count(const int* __restrict__ dst, const float* __restrict__ w,
                            float* __restrict__ deg, int* __restrict__ cnt, int e) {
    int i = blockIdx.x * blockDim.x + threadIdx.x;
    if (i < e) {
        int d = dst[i];
        atomicAdd(&deg[d], w[i]);
        atomicAdd(&cnt[d], 1);
    }
}

__global__ void k_dis(float* __restrict__ deg, int n) {
    int i = blockIdx.x * blockDim.x + threadIdx.x;
    if (i < n) {
        float d = deg[i];
        deg[i] = (d > 0.0f) ? rsqrtf(d) : 0.0f;
    }
}

// ---------------- multi-block exclusive scan: cnt[0..n) -> off[0..n] ----------------

// pass 1: per-block sums (block = 2048 elements)
__global__ __launch_bounds__(SC_TPB) void k_scan_blocks(const int* __restrict__ cnt,
                                                        int* __restrict__ bsum, int n) {
    __shared__ int red[SC_TPB / 64];
    int base = blockIdx.x * SC_TPB * SC_ITEMS;
    int s = 0;
    for (int it = 0; it < SC_ITEMS; ++it) {
        int i = base + it * SC_TPB + threadIdx.x;
        if (i < n) s += cnt[i];
    }
    for (int d = 1; d < 64; d <<= 1) s += __shfl_xor(s, d);
    if ((threadIdx.x & 63) == 0) red[threadIdx.x >> 6] = s;
    __syncthreads();
    if (threadIdx.x == 0) {
        int t = 0;
        for (int w = 0; w < SC_TPB / 64; ++w) t += red[w];
        bsum[blockIdx.x] = t;
    }
}

// pass 2: one wave exclusive-scans the <=64 block sums; also writes off[n] = total
__global__ void k_scan_bsum(int* __restrict__ bsum, int nb, int* __restrict__ off_n, int total) {
    int l = threadIdx.x;  // 64 threads
    int v = (l < nb) ? bsum[l] : 0;
    int inc = v;
    for (int d = 1; d < 64; d <<= 1) {
        int t = __shfl_up(inc, d);
        if (l >= d) inc += t;
    }
    int ex = __shfl_up(inc, 1);
    if (l == 0) ex = 0;
    if (l < nb) bsum[l] = ex;
    if (l == 0) *off_n = total;
}

// pass 3: per-block exclusive scan + block offset
__global__ __launch_bounds__(SC_TPB) void k_scan_final(const int* __restrict__ cnt,
                                                       const int* __restrict__ bsum,
                                                       int* __restrict__ off, int n) {
    __shared__ int wsum[SC_TPB / 64];
    int base = blockIdx.x * SC_TPB * SC_ITEMS;
    int tbase = base + threadIdx.x * SC_ITEMS;
    int loc[SC_ITEMS];
    int s = 0;
    for (int it = 0; it < SC_ITEMS; ++it) {
        int i = tbase + it;
        int v = (i < n) ? cnt[i] : 0;
        loc[it] = s;  // exclusive within thread
        s += v;
    }
    int l = threadIdx.x & 63, wv = threadIdx.x >> 6;
    int inc = s;
    for (int d = 1; d < 64; d <<= 1) {
        int t = __shfl_up(inc, d);
        if (l >= d) inc += t;
    }
    int thr_ex = inc - s;
    if (l == 63) wsum[wv] = inc;
    __syncthreads();
    int woff = 0;
    for (int w = 0; w < wv; ++w) woff += wsum[w];
    int pref = bsum[blockIdx.x] + woff + thr_ex;
    for (int it = 0; it < SC_ITEMS; ++it) {
        int i = tbase + it;
        if (i < n) off[i] = pref + loc[it];
    }
}

__global__ void k_zero_int(int* __restrict__ p, int n) {
    int i = blockIdx.x * blockDim.x + threadIdx.x;
    if (i < n) p[i] = 0;
}

// fill CSR: srcs[p], wnorm[p] grouped by destination
__global__ void k_fill(const int* __restrict__ src, const int* __restrict__ dst,
                       const float* __restrict__ w, const float* __restrict__ dis,
                       const int* __restrict__ off, int* __restrict__ cur,
                       int* __restrict__ srcs, float* __restrict__ wnorm, int e) {
    int i = blockIdx.x * blockDim.x + threadIdx.x;
    if (i < e) {
        int d = dst[i], s = src[i];
        int p = off[d] + atomicAdd(&cur[d], 1);
        srcs[p] = s;
        wnorm[p] = dis[s] * w[i] * dis[d];
    }
}

// ---------------- dense GEMM  Y[n,C] = relu?(X[n,K]) @ W[K,C] ----------------
// 64-row tile, 256 threads; lane owns C/4 row-accumulators; Xs reads are
// wave-uniform broadcasts (float4), Ws reads per-lane coalesced.

template <int K, int C, bool RELU>
__global__ __launch_bounds__(256) void k_gemm(const float* __restrict__ X,
                                              const float* __restrict__ W,
                                              float* __restrict__ Y, int n) {
    constexpr int RPT = C / 4;  // rows per thread
    __shared__ float Ws[K * C];
    __shared__ float Xs[64 * K];

    const int g = threadIdx.x / C;
    const int c = threadIdx.x % C;

    for (int t = threadIdx.x; t < K * C; t += 256) Ws[t] = W[t];

    const int base = blockIdx.x * 64;
    constexpr int VECS = 64 * K / 4;
    const float4* X4 = (const float4*)(X + (size_t)base * K);
    for (int v = threadIdx.x; v < VECS; v += 256) {
        int row = v / (K / 4);
        float4 val = make_float4(0.f, 0.f, 0.f, 0.f);
        if (base + row < n) val = X4[v];
        if (RELU) {
            val.x = fmaxf(val.x, 0.f); val.y = fmaxf(val.y, 0.f);
            val.z = fmaxf(val.z, 0.f); val.w = fmaxf(val.w, 0.f);
        }
        *(float4*)&Xs[v * 4] = val;
    }
    __syncthreads();

    float acc[RPT];
#pragma unroll
    for (int r = 0; r < RPT; ++r) acc[r] = 0.f;

    const int row0 = g * RPT;
#pragma unroll
    for (int k = 0; k < K; k += 4) {
        float w0 = Ws[(k + 0) * C + c];
        float w1 = Ws[(k + 1) * C + c];
        float w2 = Ws[(k + 2) * C + c];
        float w3 = Ws[(k + 3) * C + c];
#pragma unroll
        for (int r = 0; r < RPT; ++r) {
            float4 xv = *(const float4*)&Xs[(row0 + r) * K + k];
            acc[r] = fmaf(xv.x, w0, acc[r]);
            acc[r] = fmaf(xv.y, w1, acc[r]);
            acc[r] = fmaf(xv.z, w2, acc[r]);
            acc[r] = fmaf(xv.w, w3, acc[r]);
        }
    }
#pragma unroll
    for (int r = 0; r < RPT; ++r) {
        int row = base + row0 + r;
        if (row < n) Y[(size_t)row * C + c] = acc[r];
    }
}

// ---------------- CSR gather ----------------
// C=64: half-wave (32 lanes) per node, float2 channels, 2x unrolled edge loop.

__global__ __launch_bounds__(TPB) void k_gather64(const float* __restrict__ HW,
                                                  const int* __restrict__ off,
                                                  const int* __restrict__ srcs,
                                                  const float* __restrict__ wnorm,
                                                  const float* __restrict__ dis,
                                                  const float* __restrict__ b,
                                                  float* __restrict__ Y, int n) {
    int node = (blockIdx.x * blockDim.x + threadIdx.x) >> 5;
    int l = threadIdx.x & 31;
    if (node >= n) return;
    const float2* HW2 = (const float2*)HW;
    const float2* b2 = (const float2*)b;
    float dd = dis[node];
    float2 hv = HW2[node * 32 + l];
    float2 bb = b2[l];
    float ax = fmaf(dd * dd, hv.x, bb.x);
    float ay = fmaf(dd * dd, hv.y, bb.y);
    float bx = 0.f, by = 0.f;
    int j = off[node], end = off[node + 1];
    for (; j + 1 < end; j += 2) {
        int s0 = srcs[j], s1 = srcs[j + 1];
        float w0 = wnorm[j], w1 = wnorm[j + 1];
        float2 v0 = HW2[s0 * 32 + l];
        float2 v1 = HW2[s1 * 32 + l];
        ax = fmaf(w0, v0.x, ax); ay = fmaf(w0, v0.y, ay);
        bx = fmaf(w1, v1.x, bx); by = fmaf(w1, v1.y, by);
    }
    if (j < end) {
        int s0 = srcs[j];
        float w0 = wnorm[j];
        float2 v0 = HW2[s0 * 32 + l];
        ax = fmaf(w0, v0.x, ax); ay = fmaf(w0, v0.y, ay);
    }
    float2 o;
    o.x = ax + bx;
    o.y = ay + by;
    ((float2*)Y)[node * 32 + l] = o;
}

// C=32: half-wave per node, scalar channel, 2x unrolled.

__global__ __launch_bounds__(TPB) void k_gather32(const float* __restrict__ HW,
                                                  const int* __restrict__ off,
                                                  const int* __restrict__ srcs,
                                                  const float* __restrict__ wnorm,
                                                  const float* __restrict__ dis,
                                                  const float* __restrict__ b,
                                                  float* __restrict__ Y, int n) {
    int node = (blockIdx.x * blockDim.x + threadIdx.x) >> 5;
    int c = threadIdx.x & 31;
    if (node >= n) return;
    float dd = dis[node];
    float a0 = fmaf(dd * dd, HW[node * 32 + c], b[c]);
    float a1 = 0.f;
    int j = off[node], end = off[node + 1];
    for (; j + 1 < end; j += 2) {
        int s0 = srcs[j], s1 = srcs[j + 1];
        float w0 = wnorm[j], w1 = wnorm[j + 1];
        a0 = fmaf(w0, HW[s0 * 32 + c], a0);
        a1 = fmaf(w1, HW[s1 * 32 + c], a1);
    }
    if (j < end) a0 = fmaf(wnorm[j], HW[srcs[j] * 32 + c], a0);
    Y[node * 32 + c] = a0 + a1;
}

// ---------------- launch ----------------

extern "C" void kernel_launch(void* const* d_in, const int* in_sizes, int n_in,
                              void* d_out, int out_size, void* d_ws, size_t ws_size,
                              hipStream_t stream) {
    const float* x  = (const float*)d_in[0];
    const int*   ei = (const int*)d_in[1];
    const float* ew = (const float*)d_in[2];
    const float* W1 = (const float*)d_in[3];
    const float* b1 = (const float*)d_in[4];
    const float* W2 = (const float*)d_in[5];
    const float* b2 = (const float*)d_in[6];
    const float* W3 = (const float*)d_in[7];
    const float* b3 = (const float*)d_in[8];
    float* out = (float*)d_out;

    const int IN_C = 128, HID_C = 64;
    const int N = in_sizes[0] / IN_C;   // 100000
    const int E = in_sizes[2];          // 1600000

    const int* src = ei;       // edge_index[0] = row (gather source)
    const int* dst = ei + E;   // edge_index[1] = col (destination)

    // workspace layout (all 4-byte elems)
    char* w = (char*)d_ws;
    float* dis   = (float*)w;                 w += sizeof(float) * N;
    int*   off   = (int*)w;                   w += sizeof(int) * (N + 1);
    int*   cur   = (int*)w;                   w += sizeof(int) * N;
    int*   bsum  = (int*)w;                   w += sizeof(int) * 64;
    int*   srcs  = (int*)w;                   w += sizeof(int) * E;
    float* wnorm = (float*)w;                 w += sizeof(float) * E;
    float* A     = (float*)w;                 w += sizeof(float) * (size_t)N * HID_C;
    float* B     = (float*)w;                 /* N*HID_C floats */

    const int gN = (N + TPB - 1) / TPB;
    const int gE = (E + TPB - 1) / TPB;
    const int nScanBlocks = (N + SC_TPB * SC_ITEMS - 1) / (SC_TPB * SC_ITEMS);  // 49

    // ---- build normalization + CSR ----
    k_init<<<gN, TPB, 0, stream>>>(dis, cur, N);
    k_deg_count<<<gE, TPB, 0, stream>>>(dst, ew, dis, cur, E);
    k_dis<<<gN, TPB, 0, stream>>>(dis, N);
    k_scan_blocks<<<nScanBlocks, SC_TPB, 0, stream>>>(cur, bsum, N);
    k_scan_bsum<<<1, 64, 0, stream>>>(bsum, nScanBlocks, off + N, E);
    k_scan_final<<<nScanBlocks, SC_TPB, 0, stream>>>(cur, bsum, off, N);
    k_zero_int<<<gN, TPB, 0, stream>>>(cur, N);
    k_fill<<<gE, TPB, 0, stream>>>(src, dst, ew, dis, off, cur, srcs, wnorm, E);

    const int nTiles = (N + 63) / 64;
    const int gHalf = ((size_t)N * 32 + TPB - 1) / TPB;  // half-wave per node

    // ---- layer 1 ----
    k_gemm<128, 64, false><<<nTiles, 256, 0, stream>>>(x, W1, A, N);
    k_gather64<<<gHalf, TPB, 0, stream>>>(A, off, srcs, wnorm, dis, b1, B, N);

    // ---- layer 2 ----
    k_gemm<64, 64, true><<<nTiles, 256, 0, stream>>>(B, W2, A, N);
    k_gather64<<<gHalf, TPB, 0, stream>>>(A, off, srcs, wnorm, dis, b2, B, N);

    // ---- layer 3 ----
    k_gemm<64, 32, true><<<nTiles, 256, 0, stream>>>(B, W3, A, N);
    k_gather32<<<gHalf, TPB, 0, stream>>>(A, off, srcs, wnorm, dis, b3, out, N);
}

// Round 4
// 555.558 us; speedup vs baseline: 5.5173x; 5.5173x over previous
//
#include <hip/hip_runtime.h>
#include <math.h>

#define TPB 256
#define SC_TPB 256
#define SC_ITEMS 8   // 2048 elements per scan block

// ---------------- normalization + degree/count ----------------

__global__ void k_init(float* __restrict__ deg, int* __restrict__ cnt, int n) {
    int i = blockIdx.x * blockDim.x + threadIdx.x;
    if (i < n) { deg[i] = 1.0f; cnt[i] = 0; }  // self-loop weight = 1
}

__global__ void k_deg_count(const int* __restrict__ dst, const float* __restrict__ w,
                            float* __restrict__ deg, int* __restrict__ cnt, int e) {
    int i = blockIdx.x * blockDim.x + threadIdx.x;
    if (i < e) {
        int d = dst[i];
        atomicAdd(&deg[d], w[i]);
        atomicAdd(&cnt[d], 1);
    }
}

__global__ void k_dis(float* __restrict__ deg, int n) {
    int i = blockIdx.x * blockDim.x + threadIdx.x;
    if (i < n) {
        float d = deg[i];
        deg[i] = (d > 0.0f) ? rsqrtf(d) : 0.0f;
    }
}

// ---------------- multi-block exclusive scan: cnt[0..n) -> off[0..n] ----------------

__global__ __launch_bounds__(SC_TPB) void k_scan_blocks(const int* __restrict__ cnt,
                                                        int* __restrict__ bsum, int n) {
    __shared__ int red[SC_TPB / 64];
    int base = blockIdx.x * SC_TPB * SC_ITEMS;
    int s = 0;
    for (int it = 0; it < SC_ITEMS; ++it) {
        int i = base + it * SC_TPB + threadIdx.x;
        if (i < n) s += cnt[i];
    }
    for (int d = 1; d < 64; d <<= 1) s += __shfl_xor(s, d);
    if ((threadIdx.x & 63) == 0) red[threadIdx.x >> 6] = s;
    __syncthreads();
    if (threadIdx.x == 0) {
        int t = 0;
        for (int w = 0; w < SC_TPB / 64; ++w) t += red[w];
        bsum[blockIdx.x] = t;
    }
}

__global__ void k_scan_bsum(int* __restrict__ bsum, int nb, int* __restrict__ off_n, int total) {
    int l = threadIdx.x;  // 64 threads
    int v = (l < nb) ? bsum[l] : 0;
    int inc = v;
    for (int d = 1; d < 64; d <<= 1) {
        int t = __shfl_up(inc, d);
        if (l >= d) inc += t;
    }
    int ex = __shfl_up(inc, 1);
    if (l == 0) ex = 0;
    if (l < nb) bsum[l] = ex;
    if (l == 0) *off_n = total;
}

__global__ __launch_bounds__(SC_TPB) void k_scan_final(const int* __restrict__ cnt,
                                                       const int* __restrict__ bsum,
                                                       int* __restrict__ off, int n) {
    __shared__ int wsum[SC_TPB / 64];
    int base = blockIdx.x * SC_TPB * SC_ITEMS;
    int tbase = base + threadIdx.x * SC_ITEMS;
    int loc[SC_ITEMS];
    int s = 0;
    for (int it = 0; it < SC_ITEMS; ++it) {
        int i = tbase + it;
        int v = (i < n) ? cnt[i] : 0;
        loc[it] = s;
        s += v;
    }
    int l = threadIdx.x & 63, wv = threadIdx.x >> 6;
    int inc = s;
    for (int d = 1; d < 64; d <<= 1) {
        int t = __shfl_up(inc, d);
        if (l >= d) inc += t;
    }
    int thr_ex = inc - s;
    if (l == 63) wsum[wv] = inc;
    __syncthreads();
    int woff = 0;
    for (int w = 0; w < wv; ++w) woff += wsum[w];
    int pref = bsum[blockIdx.x] + woff + thr_ex;
    for (int it = 0; it < SC_ITEMS; ++it) {
        int i = tbase + it;
        if (i < n) off[i] = pref + loc[it];
    }
}

__global__ void k_zero_int(int* __restrict__ p, int n) {
    int i = blockIdx.x * blockDim.x + threadIdx.x;
    if (i < n) p[i] = 0;
}

__global__ void k_fill(const int* __restrict__ src, const int* __restrict__ dst,
                       const float* __restrict__ w, const float* __restrict__ dis,
                       const int* __restrict__ off, int* __restrict__ cur,
                       int* __restrict__ srcs, float* __restrict__ wnorm, int e) {
    int i = blockIdx.x * blockDim.x + threadIdx.x;
    if (i < e) {
        int d = dst[i], s = src[i];
        int p = off[d] + atomicAdd(&cur[d], 1);
        srcs[p] = s;
        wnorm[p] = dis[s] * w[i] * dis[d];
    }
}

// ---------------- dense GEMM  Y[n,C] = relu?(X[n,K]) @ W[K,C] ----------------
// 256 threads; thread tile 4 rows x CPT cols (CPT=8 for C=64, 4 for C=32).
// Block tile M=128 rows. K staged in 64-chunks. X tile XOR-swizzled in 16B
// blocks to kill the row-stride-4 bank conflict on b128 reads.

template <int K, int C, bool RELU>
__global__ __launch_bounds__(256) void k_gemm(const float* __restrict__ X,
                                              const float* __restrict__ W,
                                              float* __restrict__ Y, int n) {
    constexpr int CPT = (C == 32) ? 4 : 8;
    constexpr int CG = C / CPT;            // 8
    constexpr int RG = 256 / CG;           // 32
    constexpr int M = RG * 4;              // 128 rows per block
    constexpr int KC = (K > 64) ? 64 : K;  // K chunk
    constexpr int NKB = KC / 4;            // 16B k-blocks per chunk

    __shared__ float Ws[KC * C];
    __shared__ float Xs[M * KC];

    const int cg = threadIdx.x & (CG - 1);
    const int rg = threadIdx.x / CG;
    const int c0 = cg * CPT;
    const int r0 = rg * 4;
    const int base = blockIdx.x * M;

    float acc[4][CPT];
#pragma unroll
    for (int i = 0; i < 4; ++i)
#pragma unroll
        for (int j = 0; j < CPT; ++j) acc[i][j] = 0.f;

    for (int kc = 0; kc < K; kc += KC) {
        if (kc) __syncthreads();
        // stage W chunk (linear float4 copy)
        const float4* Wg4 = (const float4*)(W + (size_t)kc * C);
        for (int v = threadIdx.x; v < KC * C / 4; v += 256)
            ((float4*)Ws)[v] = Wg4[v];
        // stage X chunk, swizzled
        for (int v = threadIdx.x; v < M * NKB; v += 256) {
            int m = v / NKB, kb = v % NKB;
            int row = base + m;
            float4 val = make_float4(0.f, 0.f, 0.f, 0.f);
            if (row < n) val = *(const float4*)(X + (size_t)row * K + kc + kb * 4);
            if (RELU) {
                val.x = fmaxf(val.x, 0.f); val.y = fmaxf(val.y, 0.f);
                val.z = fmaxf(val.z, 0.f); val.w = fmaxf(val.w, 0.f);
            }
            *(float4*)&Xs[m * KC + ((kb ^ (m & 3)) << 2)] = val;
        }
        __syncthreads();

#pragma unroll 1
        for (int kb = 0; kb < NKB; ++kb) {
            const int k = kb * 4;
            float4 xv[4];
#pragma unroll
            for (int i = 0; i < 4; ++i)
                xv[i] = *(const float4*)&Xs[(r0 + i) * KC + ((kb ^ i) << 2)];
#pragma unroll
            for (int kk = 0; kk < 4; ++kk) {
                float4 wa = *(const float4*)&Ws[(k + kk) * C + c0];
                float4 wb;
                if constexpr (CPT == 8)
                    wb = *(const float4*)&Ws[(k + kk) * C + c0 + 4];
#pragma unroll
                for (int i = 0; i < 4; ++i) {
                    float xk = ((const float*)&xv[i])[kk];
                    acc[i][0] = fmaf(xk, wa.x, acc[i][0]);
                    acc[i][1] = fmaf(xk, wa.y, acc[i][1]);
                    acc[i][2] = fmaf(xk, wa.z, acc[i][2]);
                    acc[i][3] = fmaf(xk, wa.w, acc[i][3]);
                    if constexpr (CPT == 8) {
                        acc[i][4] = fmaf(xk, wb.x, acc[i][4]);
                        acc[i][5] = fmaf(xk, wb.y, acc[i][5]);
                        acc[i][6] = fmaf(xk, wb.z, acc[i][6]);
                        acc[i][7] = fmaf(xk, wb.w, acc[i][7]);
                    }
                }
            }
        }
    }

#pragma unroll
    for (int i = 0; i < 4; ++i) {
        int row = base + r0 + i;
        if (row < n) {
            *(float4*)(Y + (size_t)row * C + c0) =
                make_float4(acc[i][0], acc[i][1], acc[i][2], acc[i][3]);
            if constexpr (CPT == 8)
                *(float4*)(Y + (size_t)row * C + c0 + 4) =
                    make_float4(acc[i][4], acc[i][5], acc[i][6], acc[i][7]);
        }
    }
}

// ---------------- CSR gather ----------------
// C=64: half-wave (32 lanes) per node, float2 channels, 2x unrolled edge loop.

__global__ __launch_bounds__(TPB) void k_gather64(const float* __restrict__ HW,
                                                  const int* __restrict__ off,
                                                  const int* __restrict__ srcs,
                                                  const float* __restrict__ wnorm,
                                                  const float* __restrict__ dis,
                                                  const float* __restrict__ b,
                                                  float* __restrict__ Y, int n) {
    int node = (blockIdx.x * blockDim.x + threadIdx.x) >> 5;
    int l = threadIdx.x & 31;
    if (node >= n) return;
    const float2* HW2 = (const float2*)HW;
    const float2* b2 = (const float2*)b;
    float dd = dis[node];
    float2 hv = HW2[node * 32 + l];
    float2 bb = b2[l];
    float ax = fmaf(dd * dd, hv.x, bb.x);
    float ay = fmaf(dd * dd, hv.y, bb.y);
    float bx = 0.f, by = 0.f;
    int j = off[node], end = off[node + 1];
    for (; j + 1 < end; j += 2) {
        int s0 = srcs[j], s1 = srcs[j + 1];
        float w0 = wnorm[j], w1 = wnorm[j + 1];
        float2 v0 = HW2[s0 * 32 + l];
        float2 v1 = HW2[s1 * 32 + l];
        ax = fmaf(w0, v0.x, ax); ay = fmaf(w0, v0.y, ay);
        bx = fmaf(w1, v1.x, bx); by = fmaf(w1, v1.y, by);
    }
    if (j < end) {
        int s0 = srcs[j];
        float w0 = wnorm[j];
        float2 v0 = HW2[s0 * 32 + l];
        ax = fmaf(w0, v0.x, ax); ay = fmaf(w0, v0.y, ay);
    }
    float2 o;
    o.x = ax + bx;
    o.y = ay + by;
    ((float2*)Y)[node * 32 + l] = o;
}

// C=32: half-wave per node, scalar channel, 2x unrolled.

__global__ __launch_bounds__(TPB) void k_gather32(const float* __restrict__ HW,
                                                  const int* __restrict__ off,
                                                  const int* __restrict__ srcs,
                                                  const float* __restrict__ wnorm,
                                                  const float* __restrict__ dis,
                                                  const float* __restrict__ b,
                                                  float* __restrict__ Y, int n) {
    int node = (blockIdx.x * blockDim.x + threadIdx.x) >> 5;
    int c = threadIdx.x & 31;
    if (node >= n) return;
    float dd = dis[node];
    float a0 = fmaf(dd * dd, HW[node * 32 + c], b[c]);
    float a1 = 0.f;
    int j = off[node], end = off[node + 1];
    for (; j + 1 < end; j += 2) {
        int s0 = srcs[j], s1 = srcs[j + 1];
        float w0 = wnorm[j], w1 = wnorm[j + 1];
        a0 = fmaf(w0, HW[s0 * 32 + c], a0);
        a1 = fmaf(w1, HW[s1 * 32 + c], a1);
    }
    if (j < end) a0 = fmaf(wnorm[j], HW[srcs[j] * 32 + c], a0);
    Y[node * 32 + c] = a0 + a1;
}

// ---------------- launch ----------------

extern "C" void kernel_launch(void* const* d_in, const int* in_sizes, int n_in,
                              void* d_out, int out_size, void* d_ws, size_t ws_size,
                              hipStream_t stream) {
    const float* x  = (const float*)d_in[0];
    const int*   ei = (const int*)d_in[1];
    const float* ew = (const float*)d_in[2];
    const float* W1 = (const float*)d_in[3];
    const float* b1 = (const float*)d_in[4];
    const float* W2 = (const float*)d_in[5];
    const float* b2 = (const float*)d_in[6];
    const float* W3 = (const float*)d_in[7];
    const float* b3 = (const float*)d_in[8];
    float* out = (float*)d_out;

    const int IN_C = 128, HID_C = 64;
    const int N = in_sizes[0] / IN_C;   // 100000
    const int E = in_sizes[2];          // 1600000

    const int* src = ei;       // edge_index[0] = row (gather source)
    const int* dst = ei + E;   // edge_index[1] = col (destination)

    // workspace layout (all 4-byte elems)
    char* w = (char*)d_ws;
    float* dis   = (float*)w;                 w += sizeof(float) * N;
    int*   off   = (int*)w;                   w += sizeof(int) * (N + 1);
    int*   cur   = (int*)w;                   w += sizeof(int) * N;
    int*   bsum  = (int*)w;                   w += sizeof(int) * 64;
    int*   srcs  = (int*)w;                   w += sizeof(int) * E;
    float* wnorm = (float*)w;                 w += sizeof(float) * E;
    float* A     = (float*)w;                 w += sizeof(float) * (size_t)N * HID_C;
    float* B     = (float*)w;                 /* N*HID_C floats */

    const int gN = (N + TPB - 1) / TPB;
    const int gE = (E + TPB - 1) / TPB;
    const int nScanBlocks = (N + SC_TPB * SC_ITEMS - 1) / (SC_TPB * SC_ITEMS);  // 49

    // ---- build normalization + CSR ----
    k_init<<<gN, TPB, 0, stream>>>(dis, cur, N);
    k_deg_count<<<gE, TPB, 0, stream>>>(dst, ew, dis, cur, E);
    k_dis<<<gN, TPB, 0, stream>>>(dis, N);
    k_scan_blocks<<<nScanBlocks, SC_TPB, 0, stream>>>(cur, bsum, N);
    k_scan_bsum<<<1, 64, 0, stream>>>(bsum, nScanBlocks, off + N, E);
    k_scan_final<<<nScanBlocks, SC_TPB, 0, stream>>>(cur, bsum, off, N);
    k_zero_int<<<gN, TPB, 0, stream>>>(cur, N);
    k_fill<<<gE, TPB, 0, stream>>>(src, dst, ew, dis, off, cur, srcs, wnorm, E);

    const int nTiles = (N + 127) / 128;
    const int gHalf = (N * 32 + TPB - 1) / TPB;  // half-wave per node

    // ---- layer 1 ----
    k_gemm<128, 64, false><<<nTiles, 256, 0, stream>>>(x, W1, A, N);
    k_gather64<<<gHalf, TPB, 0, stream>>>(A, off, srcs, wnorm, dis, b1, B, N);

    // ---- layer 2 ----
    k_gemm<64, 64, true><<<nTiles, 256, 0, stream>>>(B, W2, A, N);
    k_gather64<<<gHalf, TPB, 0, stream>>>(A, off, srcs, wnorm, dis, b2, B, N);

    // ---- layer 3 ----
    k_gemm<64, 32, true><<<nTiles, 256, 0, stream>>>(B, W3, A, N);
    k_gather32<<<gHalf, TPB, 0, stream>>>(A, off, srcs, wnorm, dis, b3, out, N);
}

// Round 5
// 393.016 us; speedup vs baseline: 7.7991x; 1.4136x over previous
//
#include <hip/hip_runtime.h>
#include <math.h>

#define TPB 256
#define SC_TPB 256
#define SC_ITEMS 8   // 2048 elements per scan block
#define CH 4096      // edges per bucket-pass block
#define BKT 512      // nodes per bucket (bucket = dst >> 9)

// ---------------- multi-block exclusive scan (generic, in-place safe) ----------------

__global__ __launch_bounds__(SC_TPB) void k_scan_blocks(const int* __restrict__ cnt,
                                                        int* __restrict__ bsum, int n) {
    __shared__ int red[SC_TPB / 64];
    int base = blockIdx.x * SC_TPB * SC_ITEMS;
    int s = 0;
    for (int it = 0; it < SC_ITEMS; ++it) {
        int i = base + it * SC_TPB + threadIdx.x;
        if (i < n) s += cnt[i];
    }
    for (int d = 1; d < 64; d <<= 1) s += __shfl_xor(s, d);
    if ((threadIdx.x & 63) == 0) red[threadIdx.x >> 6] = s;
    __syncthreads();
    if (threadIdx.x == 0) {
        int t = 0;
        for (int w = 0; w < SC_TPB / 64; ++w) t += red[w];
        bsum[blockIdx.x] = t;
    }
}

__global__ void k_scan_bsum(int* __restrict__ bsum, int nb, int* __restrict__ off_n, int total) {
    int l = threadIdx.x;  // 64 threads
    int v = (l < nb) ? bsum[l] : 0;
    int inc = v;
    for (int d = 1; d < 64; d <<= 1) {
        int t = __shfl_up(inc, d);
        if (l >= d) inc += t;
    }
    int ex = __shfl_up(inc, 1);
    if (l == 0) ex = 0;
    if (l < nb) bsum[l] = ex;
    if (l == 0) *off_n = total;
}

__global__ __launch_bounds__(SC_TPB) void k_scan_final(const int* __restrict__ cnt,
                                                       const int* __restrict__ bsum,
                                                       int* __restrict__ off, int n) {
    __shared__ int wsum[SC_TPB / 64];
    int base = blockIdx.x * SC_TPB * SC_ITEMS;
    int tbase = base + threadIdx.x * SC_ITEMS;
    int loc[SC_ITEMS];
    int s = 0;
    for (int it = 0; it < SC_ITEMS; ++it) {
        int i = tbase + it;
        int v = (i < n) ? cnt[i] : 0;
        loc[it] = s;
        s += v;
    }
    int l = threadIdx.x & 63, wv = threadIdx.x >> 6;
    int inc = s;
    for (int d = 1; d < 64; d <<= 1) {
        int t = __shfl_up(inc, d);
        if (l >= d) inc += t;
    }
    int thr_ex = inc - s;
    if (l == 63) wsum[wv] = inc;
    __syncthreads();
    int woff = 0;
    for (int w = 0; w < wv; ++w) woff += wsum[w];
    int pref = bsum[blockIdx.x] + woff + thr_ex;
    for (int it = 0; it < SC_ITEMS; ++it) {
        int i = tbase + it;
        if (i < n) off[i] = pref + loc[it];
    }
}

// ---------------- bucket pass 1: per-(bucket, block) counts, LDS histogram ----------------
// M[b * nblk + blk] = #edges in block blk with dst in bucket b.  No global atomics.

__global__ __launch_bounds__(256) void k_bucket_count(const int* __restrict__ dst,
                                                      int* __restrict__ M,
                                                      int e, int nb, int nblk) {
    __shared__ int h[256];  // nb <= 256 (N <= 131072)
    for (int i = threadIdx.x; i < nb; i += 256) h[i] = 0;
    __syncthreads();
    int base = blockIdx.x * CH;
    int lim = min(base + CH, e);
    for (int i = base + threadIdx.x; i < lim; i += 256)
        atomicAdd(&h[dst[i] >> 9], 1);
    __syncthreads();
    for (int b = threadIdx.x; b < nb; b += 256)
        M[b * nblk + blockIdx.x] = h[b];
}

// bucketStart[b] = scanned M[b * nblk]; bucketStart[nb] = e
__global__ void k_bucket_start(const int* __restrict__ Ms, int* __restrict__ bucketStart,
                               int nb, int nblk, int e) {
    int b = blockIdx.x * blockDim.x + threadIdx.x;
    if (b < nb) bucketStart[b] = Ms[b * nblk];
    if (b == nb) bucketStart[nb] = e;
}

// ---------------- bucket pass 2: scatter edges into bucket regions ----------------

__global__ __launch_bounds__(256) void k_bucket_scatter(const int* __restrict__ src,
                                                        const int* __restrict__ dst,
                                                        const float* __restrict__ w,
                                                        const int* __restrict__ Ms,
                                                        int4* __restrict__ barr,
                                                        int e, int nb, int nblk) {
    __shared__ int cur[256];
    for (int i = threadIdx.x; i < nb; i += 256) cur[i] = Ms[i * nblk + blockIdx.x];
    __syncthreads();
    int base = blockIdx.x * CH;
    int lim = min(base + CH, e);
    for (int i = base + threadIdx.x; i < lim; i += 256) {
        int d = dst[i];
        int p = atomicAdd(&cur[d >> 9], 1);  // LDS cursor
        barr[p] = make_int4(src[i], d, __float_as_int(w[i]), 0);
    }
}

// ---------------- bucket pass 3: per-bucket CSR build + degree/dis ----------------
// One block per bucket of 512 nodes.  All LDS atomics; computes dis, off, srcs, wtmp.

__global__ __launch_bounds__(256) void k_csr_build(const int4* __restrict__ barr,
                                                   const int* __restrict__ bucketStart,
                                                   float* __restrict__ dis,
                                                   int* __restrict__ off,
                                                   int* __restrict__ srcs,
                                                   float* __restrict__ wtmp, int n) {
    int b = blockIdx.x;
    int nbase = b << 9;
    int ebeg = bucketStart[b], eend = bucketStart[b + 1];
    __shared__ int cnt[BKT];
    __shared__ float wsum[BKT];
    __shared__ float disL[BKT];
    __shared__ int scn[BKT];
    __shared__ int wtot[4];

    for (int i = threadIdx.x; i < BKT; i += 256) { cnt[i] = 0; wsum[i] = 0.f; }
    __syncthreads();
    for (int j = ebeg + threadIdx.x; j < eend; j += 256) {
        int4 ed = barr[j];
        int dl = ed.y - nbase;
        atomicAdd(&cnt[dl], 1);
        atomicAdd(&wsum[dl], __int_as_float(ed.z));
    }
    __syncthreads();

    // exclusive scan of cnt[0..511] with 256 threads (pair per thread)
    int t = threadIdx.x;
    int a0 = cnt[2 * t], a1 = cnt[2 * t + 1];
    int s = a0 + a1;
    int l = t & 63, wv = t >> 6;
    int inc = s;
    for (int d = 1; d < 64; d <<= 1) {
        int u = __shfl_up(inc, d);
        if (l >= d) inc += u;
    }
    if (l == 63) wtot[wv] = inc;
    // dis while scan waves finish
    for (int i = threadIdx.x; i < BKT; i += 256) {
        int node = nbase + i;
        if (node < n) {
            float dv = rsqrtf(1.0f + wsum[i]);  // deg = 1 (self-loop) + sum(w) > 0
            disL[i] = dv;
            dis[node] = dv;
        }
    }
    __syncthreads();
    int woff = 0;
    for (int k = 0; k < wv; ++k) woff += wtot[k];
    int ex = woff + inc - s;
    scn[2 * t] = ex;
    scn[2 * t + 1] = ex + a0;
    __syncthreads();
    for (int i = threadIdx.x; i < BKT; i += 256) {
        int node = nbase + i;
        if (node < n) off[node] = ebeg + scn[i];
    }
    __syncthreads();
    // cursor phase: scn doubles as cursor
    for (int j = ebeg + threadIdx.x; j < eend; j += 256) {
        int4 ed = barr[j];
        int dl = ed.y - nbase;
        int p = ebeg + atomicAdd(&scn[dl], 1);
        srcs[p] = ed.x;
        wtmp[p] = __int_as_float(ed.z) * disL[dl];
    }
}

// finalize: wnorm[p] = wtmp[p] * dis[src[p]]   (in-place on wtmp buffer)
__global__ void k_wnorm(const int* __restrict__ srcs, float* __restrict__ wnorm,
                        const float* __restrict__ dis, int e) {
    int i = blockIdx.x * blockDim.x + threadIdx.x;
    if (i < e) wnorm[i] *= dis[srcs[i]];
}

// ---------------- dense GEMM  Y[n,C] = relu?(X[n,K]) @ W[K,C] ----------------

template <int K, int C, bool RELU>
__global__ __launch_bounds__(256) void k_gemm(const float* __restrict__ X,
                                              const float* __restrict__ W,
                                              float* __restrict__ Y, int n) {
    constexpr int CPT = (C == 32) ? 4 : 8;
    constexpr int CG = C / CPT;            // 8
    constexpr int RG = 256 / CG;           // 32
    constexpr int M = RG * 4;              // 128 rows per block
    constexpr int KC = (K > 64) ? 64 : K;  // K chunk
    constexpr int NKB = KC / 4;            // 16B k-blocks per chunk

    __shared__ float Ws[KC * C];
    __shared__ float Xs[M * KC];

    const int cg = threadIdx.x & (CG - 1);
    const int rg = threadIdx.x / CG;
    const int c0 = cg * CPT;
    const int r0 = rg * 4;
    const int base = blockIdx.x * M;

    float acc[4][CPT];
#pragma unroll
    for (int i = 0; i < 4; ++i)
#pragma unroll
        for (int j = 0; j < CPT; ++j) acc[i][j] = 0.f;

    for (int kc = 0; kc < K; kc += KC) {
        if (kc) __syncthreads();
        const float4* Wg4 = (const float4*)(W + (size_t)kc * C);
        for (int v = threadIdx.x; v < KC * C / 4; v += 256)
            ((float4*)Ws)[v] = Wg4[v];
        for (int v = threadIdx.x; v < M * NKB; v += 256) {
            int m = v / NKB, kb = v % NKB;
            int row = base + m;
            float4 val = make_float4(0.f, 0.f, 0.f, 0.f);
            if (row < n) val = *(const float4*)(X + (size_t)row * K + kc + kb * 4);
            if (RELU) {
                val.x = fmaxf(val.x, 0.f); val.y = fmaxf(val.y, 0.f);
                val.z = fmaxf(val.z, 0.f); val.w = fmaxf(val.w, 0.f);
            }
            *(float4*)&Xs[m * KC + ((kb ^ (m & 3)) << 2)] = val;
        }
        __syncthreads();

#pragma unroll 1
        for (int kb = 0; kb < NKB; ++kb) {
            const int k = kb * 4;
            float4 xv[4];
#pragma unroll
            for (int i = 0; i < 4; ++i)
                xv[i] = *(const float4*)&Xs[(r0 + i) * KC + ((kb ^ i) << 2)];
#pragma unroll
            for (int kk = 0; kk < 4; ++kk) {
                float4 wa = *(const float4*)&Ws[(k + kk) * C + c0];
                float4 wb;
                if constexpr (CPT == 8)
                    wb = *(const float4*)&Ws[(k + kk) * C + c0 + 4];
#pragma unroll
                for (int i = 0; i < 4; ++i) {
                    float xk = ((const float*)&xv[i])[kk];
                    acc[i][0] = fmaf(xk, wa.x, acc[i][0]);
                    acc[i][1] = fmaf(xk, wa.y, acc[i][1]);
                    acc[i][2] = fmaf(xk, wa.z, acc[i][2]);
                    acc[i][3] = fmaf(xk, wa.w, acc[i][3]);
                    if constexpr (CPT == 8) {
                        acc[i][4] = fmaf(xk, wb.x, acc[i][4]);
                        acc[i][5] = fmaf(xk, wb.y, acc[i][5]);
                        acc[i][6] = fmaf(xk, wb.z, acc[i][6]);
                        acc[i][7] = fmaf(xk, wb.w, acc[i][7]);
                    }
                }
            }
        }
    }

#pragma unroll
    for (int i = 0; i < 4; ++i) {
        int row = base + r0 + i;
        if (row < n) {
            *(float4*)(Y + (size_t)row * C + c0) =
                make_float4(acc[i][0], acc[i][1], acc[i][2], acc[i][3]);
            if constexpr (CPT == 8)
                *(float4*)(Y + (size_t)row * C + c0 + 4) =
                    make_float4(acc[i][4], acc[i][5], acc[i][6], acc[i][7]);
        }
    }
}

// ---------------- CSR gather ----------------

__global__ __launch_bounds__(TPB) void k_gather64(const float* __restrict__ HW,
                                                  const int* __restrict__ off,
                                                  const int* __restrict__ srcs,
                                                  const float* __restrict__ wnorm,
                                                  const float* __restrict__ dis,
                                                  const float* __restrict__ b,
                                                  float* __restrict__ Y, int n) {
    int node = (blockIdx.x * blockDim.x + threadIdx.x) >> 5;
    int l = threadIdx.x & 31;
    if (node >= n) return;
    const float2* HW2 = (const float2*)HW;
    const float2* b2 = (const float2*)b;
    float dd = dis[node];
    float2 hv = HW2[node * 32 + l];
    float2 bb = b2[l];
    float ax = fmaf(dd * dd, hv.x, bb.x);
    float ay = fmaf(dd * dd, hv.y, bb.y);
    float bx = 0.f, by = 0.f;
    int j = off[node], end = off[node + 1];
    for (; j + 1 < end; j += 2) {
        int s0 = srcs[j], s1 = srcs[j + 1];
        float w0 = wnorm[j], w1 = wnorm[j + 1];
        float2 v0 = HW2[s0 * 32 + l];
        float2 v1 = HW2[s1 * 32 + l];
        ax = fmaf(w0, v0.x, ax); ay = fmaf(w0, v0.y, ay);
        bx = fmaf(w1, v1.x, bx); by = fmaf(w1, v1.y, by);
    }
    if (j < end) {
        int s0 = srcs[j];
        float w0 = wnorm[j];
        float2 v0 = HW2[s0 * 32 + l];
        ax = fmaf(w0, v0.x, ax); ay = fmaf(w0, v0.y, ay);
    }
    float2 o;
    o.x = ax + bx;
    o.y = ay + by;
    ((float2*)Y)[node * 32 + l] = o;
}

__global__ __launch_bounds__(TPB) void k_gather32(const float* __restrict__ HW,
                                                  const int* __restrict__ off,
                                                  const int* __restrict__ srcs,
                                                  const float* __restrict__ wnorm,
                                                  const float* __restrict__ dis,
                                                  const float* __restrict__ b,
                                                  float* __restrict__ Y, int n) {
    int node = (blockIdx.x * blockDim.x + threadIdx.x) >> 5;
    int c = threadIdx.x & 31;
    if (node >= n) return;
    float dd = dis[node];
    float a0 = fmaf(dd * dd, HW[node * 32 + c], b[c]);
    float a1 = 0.f;
    int j = off[node], end = off[node + 1];
    for (; j + 1 < end; j += 2) {
        int s0 = srcs[j], s1 = srcs[j + 1];
        float w0 = wnorm[j], w1 = wnorm[j + 1];
        a0 = fmaf(w0, HW[s0 * 32 + c], a0);
        a1 = fmaf(w1, HW[s1 * 32 + c], a1);
    }
    if (j < end) a0 = fmaf(wnorm[j], HW[srcs[j] * 32 + c], a0);
    Y[node * 32 + c] = a0 + a1;
}

// ---------------- launch ----------------

extern "C" void kernel_launch(void* const* d_in, const int* in_sizes, int n_in,
                              void* d_out, int out_size, void* d_ws, size_t ws_size,
                              hipStream_t stream) {
    const float* x  = (const float*)d_in[0];
    const int*   ei = (const int*)d_in[1];
    const float* ew = (const float*)d_in[2];
    const float* W1 = (const float*)d_in[3];
    const float* b1 = (const float*)d_in[4];
    const float* W2 = (const float*)d_in[5];
    const float* b2 = (const float*)d_in[6];
    const float* W3 = (const float*)d_in[7];
    const float* b3 = (const float*)d_in[8];
    float* out = (float*)d_out;

    const int IN_C = 128, HID_C = 64;
    const int N = in_sizes[0] / IN_C;   // 100000
    const int E = in_sizes[2];          // 1600000

    const int* src = ei;       // edge_index[0] = row (gather source)
    const int* dst = ei + E;   // edge_index[1] = col (destination)

    const int NB   = (N + BKT - 1) / BKT;        // 196 buckets (<=256 required)
    const int NBLK = (E + CH - 1) / CH;          // 391 chunk-blocks
    const int LM   = NB * NBLK;                  // count-matrix size

    // ---- workspace layout ----
    // persistent region: dis, off, bucketStart, bsum, srcs, wnorm
    char* w = (char*)d_ws;
    float* dis   = (float*)w;                 w += sizeof(float) * N;
    int*   off   = (int*)w;                   w += sizeof(int) * (N + 1);
    int*   bkst  = (int*)w;                   w += sizeof(int) * (NB + 1);
    int*   bsum  = (int*)w;                   w += sizeof(int) * 64;
    int*   srcs  = (int*)w;                   w += sizeof(int) * E;
    float* wnorm = (float*)w;                 w += sizeof(float) * E;
    // transient region: [M | barr] overlapped later by [A | B]
    char* w2 = (char*)(((size_t)w + 15) & ~(size_t)15);
    int*  M    = (int*)w2;
    int4* barr = (int4*)(((size_t)(M + LM) + 15) & ~(size_t)15);   // E int4
    float* A   = (float*)w2;                                       // N*64
    float* B   = A + (size_t)N * HID_C;                            // N*64

    const int nScanM = (LM + SC_TPB * SC_ITEMS - 1) / (SC_TPB * SC_ITEMS);  // 38 <= 64

    // ---- build CSR + normalization (no global atomics) ----
    k_bucket_count<<<NBLK, 256, 0, stream>>>(dst, M, E, NB, NBLK);
    k_scan_blocks<<<nScanM, SC_TPB, 0, stream>>>(M, bsum, LM);
    k_scan_bsum<<<1, 64, 0, stream>>>(bsum, nScanM, off + N, E);   // also off[N] = E
    k_scan_final<<<nScanM, SC_TPB, 0, stream>>>(M, bsum, M, LM);   // in-place scan
    k_bucket_start<<<(NB + 256) / 256, 256, 0, stream>>>(M, bkst, NB, NBLK, E);
    k_bucket_scatter<<<NBLK, 256, 0, stream>>>(src, dst, ew, M, barr, E, NB, NBLK);
    k_csr_build<<<NB, 256, 0, stream>>>(barr, bkst, dis, off, srcs, wnorm, N);
    k_wnorm<<<(E + 255) / 256, 256, 0, stream>>>(srcs, wnorm, dis, E);

    const int nTiles = (N + 127) / 128;
    const int gHalf = (N * 32 + TPB - 1) / TPB;  // half-wave per node

    // ---- layer 1 ----
    k_gemm<128, 64, false><<<nTiles, 256, 0, stream>>>(x, W1, A, N);
    k_gather64<<<gHalf, TPB, 0, stream>>>(A, off, srcs, wnorm, dis, b1, B, N);

    // ---- layer 2 ----
    k_gemm<64, 64, true><<<nTiles, 256, 0, stream>>>(B, W2, A, N);
    k_gather64<<<gHalf, TPB, 0, stream>>>(A, off, srcs, wnorm, dis, b2, B, N);

    // ---- layer 3 ----
    k_gemm<64, 32, true><<<nTiles, 256, 0, stream>>>(B, W3, A, N);
    k_gather32<<<gHalf, TPB, 0, stream>>>(A, off, srcs, wnorm, dis, b3, out, N);
}

// Round 6
// 378.994 us; speedup vs baseline: 8.0876x; 1.0370x over previous
//
#include <hip/hip_runtime.h>
#include <math.h>

#define TPB 256
#define SC_TPB 256
#define SC_ITEMS 8   // 2048 elements per scan block
#define CH 4096      // edges per bucket-pass block
#define BKT 512      // nodes per bucket (bucket = dst >> 9)

// ---------------- multi-block exclusive scan (generic, in-place safe) ----------------

__global__ __launch_bounds__(SC_TPB) void k_scan_blocks(const int* __restrict__ cnt,
                                                        int* __restrict__ bsum, int n) {
    __shared__ int red[SC_TPB / 64];
    int base = blockIdx.x * SC_TPB * SC_ITEMS;
    int s = 0;
    for (int it = 0; it < SC_ITEMS; ++it) {
        int i = base + it * SC_TPB + threadIdx.x;
        if (i < n) s += cnt[i];
    }
    for (int d = 1; d < 64; d <<= 1) s += __shfl_xor(s, d);
    if ((threadIdx.x & 63) == 0) red[threadIdx.x >> 6] = s;
    __syncthreads();
    if (threadIdx.x == 0) {
        int t = 0;
        for (int w = 0; w < SC_TPB / 64; ++w) t += red[w];
        bsum[blockIdx.x] = t;
    }
}

__global__ void k_scan_bsum(int* __restrict__ bsum, int nb, int* __restrict__ off_n, int total) {
    int l = threadIdx.x;  // 64 threads
    int v = (l < nb) ? bsum[l] : 0;
    int inc = v;
    for (int d = 1; d < 64; d <<= 1) {
        int t = __shfl_up(inc, d);
        if (l >= d) inc += t;
    }
    int ex = __shfl_up(inc, 1);
    if (l == 0) ex = 0;
    if (l < nb) bsum[l] = ex;
    if (l == 0) *off_n = total;
}

__global__ __launch_bounds__(SC_TPB) void k_scan_final(const int* __restrict__ cnt,
                                                       const int* __restrict__ bsum,
                                                       int* __restrict__ off, int n) {
    __shared__ int wsum[SC_TPB / 64];
    int base = blockIdx.x * SC_TPB * SC_ITEMS;
    int tbase = base + threadIdx.x * SC_ITEMS;
    int loc[SC_ITEMS];
    int s = 0;
    for (int it = 0; it < SC_ITEMS; ++it) {
        int i = tbase + it;
        int v = (i < n) ? cnt[i] : 0;
        loc[it] = s;
        s += v;
    }
    int l = threadIdx.x & 63, wv = threadIdx.x >> 6;
    int inc = s;
    for (int d = 1; d < 64; d <<= 1) {
        int t = __shfl_up(inc, d);
        if (l >= d) inc += t;
    }
    int thr_ex = inc - s;
    if (l == 63) wsum[wv] = inc;
    __syncthreads();
    int woff = 0;
    for (int w = 0; w < wv; ++w) woff += wsum[w];
    int pref = bsum[blockIdx.x] + woff + thr_ex;
    for (int it = 0; it < SC_ITEMS; ++it) {
        int i = tbase + it;
        if (i < n) off[i] = pref + loc[it];
    }
}

// ---------------- bucket pass 1: per-(bucket, block) counts, LDS histogram ----------------

__global__ __launch_bounds__(256) void k_bucket_count(const int* __restrict__ dst,
                                                      int* __restrict__ M,
                                                      int e, int nb, int nblk) {
    __shared__ int h[256];  // nb <= 256 (N <= 131072)
    for (int i = threadIdx.x; i < nb; i += 256) h[i] = 0;
    __syncthreads();
    int base = blockIdx.x * CH;
    int lim = min(base + CH, e);
    for (int i = base + threadIdx.x; i < lim; i += 256)
        atomicAdd(&h[dst[i] >> 9], 1);
    __syncthreads();
    for (int b = threadIdx.x; b < nb; b += 256)
        M[b * nblk + blockIdx.x] = h[b];
}

__global__ void k_bucket_start(const int* __restrict__ Ms, int* __restrict__ bucketStart,
                               int nb, int nblk, int e) {
    int b = blockIdx.x * blockDim.x + threadIdx.x;
    if (b < nb) bucketStart[b] = Ms[b * nblk];
    if (b == nb) bucketStart[nb] = e;
}

// ---------------- bucket pass 2: scatter packed edges into bucket regions ----------------
// packed: src (17 bits, N<=131072) | dst_local (9 bits) << 17

__global__ __launch_bounds__(256) void k_bucket_scatter(const int* __restrict__ src,
                                                        const int* __restrict__ dst,
                                                        const float* __restrict__ w,
                                                        const int* __restrict__ Ms,
                                                        int2* __restrict__ barr,
                                                        int e, int nb, int nblk) {
    __shared__ int cur[256];
    for (int i = threadIdx.x; i < nb; i += 256) cur[i] = Ms[i * nblk + blockIdx.x];
    __syncthreads();
    int base = blockIdx.x * CH;
    int lim = min(base + CH, e);
    for (int i = base + threadIdx.x; i < lim; i += 256) {
        int d = dst[i];
        int p = atomicAdd(&cur[d >> 9], 1);  // LDS cursor
        barr[p] = make_int2(src[i] | ((d & 511) << 17), __float_as_int(w[i]));
    }
}

// ---------------- bucket pass 3: per-bucket CSR build + degree/dis ----------------

__global__ __launch_bounds__(256) void k_csr_build(const int2* __restrict__ barr,
                                                   const int* __restrict__ bucketStart,
                                                   float* __restrict__ dis,
                                                   int* __restrict__ off,
                                                   int* __restrict__ srcs,
                                                   float* __restrict__ wtmp, int n) {
    int b = blockIdx.x;
    int nbase = b << 9;
    int ebeg = bucketStart[b], eend = bucketStart[b + 1];
    __shared__ int cnt[BKT];
    __shared__ float wsum[BKT];
    __shared__ float disL[BKT];
    __shared__ int scn[BKT];
    __shared__ int wtot[4];

    for (int i = threadIdx.x; i < BKT; i += 256) { cnt[i] = 0; wsum[i] = 0.f; }
    __syncthreads();
    for (int j = ebeg + threadIdx.x; j < eend; j += 256) {
        int2 ed = barr[j];
        int dl = ed.x >> 17;
        atomicAdd(&cnt[dl], 1);
        atomicAdd(&wsum[dl], __int_as_float(ed.y));
    }
    __syncthreads();

    // exclusive scan of cnt[0..511] with 256 threads (pair per thread)
    int t = threadIdx.x;
    int a0 = cnt[2 * t], a1 = cnt[2 * t + 1];
    int s = a0 + a1;
    int l = t & 63, wv = t >> 6;
    int inc = s;
    for (int d = 1; d < 64; d <<= 1) {
        int u = __shfl_up(inc, d);
        if (l >= d) inc += u;
    }
    if (l == 63) wtot[wv] = inc;
    for (int i = threadIdx.x; i < BKT; i += 256) {
        int node = nbase + i;
        if (node < n) {
            float dv = rsqrtf(1.0f + wsum[i]);  // deg = 1 (self-loop) + sum(w) > 0
            disL[i] = dv;
            dis[node] = dv;
        }
    }
    __syncthreads();
    int woff = 0;
    for (int k = 0; k < wv; ++k) woff += wtot[k];
    int ex = woff + inc - s;
    scn[2 * t] = ex;
    scn[2 * t + 1] = ex + a0;
    __syncthreads();
    for (int i = threadIdx.x; i < BKT; i += 256) {
        int node = nbase + i;
        if (node < n) off[node] = ebeg + scn[i];
    }
    __syncthreads();
    // cursor phase: scn doubles as cursor
    for (int j = ebeg + threadIdx.x; j < eend; j += 256) {
        int2 ed = barr[j];
        int dl = ed.x >> 17;
        int p = ebeg + atomicAdd(&scn[dl], 1);
        srcs[p] = ed.x & 0x1FFFF;
        wtmp[p] = __int_as_float(ed.y) * disL[dl];
    }
}

// finalize: wnorm[p] = wtmp[p] * dis[src[p]]
__global__ void k_wnorm(const int* __restrict__ srcs, float* __restrict__ wnorm,
                        const float* __restrict__ dis, int e) {
    int i = blockIdx.x * blockDim.x + threadIdx.x;
    if (i < e) wnorm[i] *= dis[srcs[i]];
}

// ---------------- dense GEMM  Y[n,C] = relu?(X[n,K]) @ W[K,C] ----------------

template <int K, int C, bool RELU>
__global__ __launch_bounds__(256) void k_gemm(const float* __restrict__ X,
                                              const float* __restrict__ W,
                                              float* __restrict__ Y, int n) {
    constexpr int CPT = (C == 32) ? 4 : 8;
    constexpr int CG = C / CPT;            // 8
    constexpr int RG = 256 / CG;           // 32
    constexpr int M = RG * 4;              // 128 rows per block
    constexpr int KC = (K > 64) ? 64 : K;  // K chunk
    constexpr int NKB = KC / 4;            // 16B k-blocks per chunk

    __shared__ float Ws[KC * C];
    __shared__ float Xs[M * KC];

    const int cg = threadIdx.x & (CG - 1);
    const int rg = threadIdx.x / CG;
    const int c0 = cg * CPT;
    const int r0 = rg * 4;
    const int base = blockIdx.x * M;

    float acc[4][CPT];
#pragma unroll
    for (int i = 0; i < 4; ++i)
#pragma unroll
        for (int j = 0; j < CPT; ++j) acc[i][j] = 0.f;

    for (int kc = 0; kc < K; kc += KC) {
        if (kc) __syncthreads();
        const float4* Wg4 = (const float4*)(W + (size_t)kc * C);
        for (int v = threadIdx.x; v < KC * C / 4; v += 256)
            ((float4*)Ws)[v] = Wg4[v];
        for (int v = threadIdx.x; v < M * NKB; v += 256) {
            int m = v / NKB, kb = v % NKB;
            int row = base + m;
            float4 val = make_float4(0.f, 0.f, 0.f, 0.f);
            if (row < n) val = *(const float4*)(X + (size_t)row * K + kc + kb * 4);
            if (RELU) {
                val.x = fmaxf(val.x, 0.f); val.y = fmaxf(val.y, 0.f);
                val.z = fmaxf(val.z, 0.f); val.w = fmaxf(val.w, 0.f);
            }
            *(float4*)&Xs[m * KC + ((kb ^ (m & 3)) << 2)] = val;
        }
        __syncthreads();

#pragma unroll 1
        for (int kb = 0; kb < NKB; ++kb) {
            const int k = kb * 4;
            float4 xv[4];
#pragma unroll
            for (int i = 0; i < 4; ++i)
                xv[i] = *(const float4*)&Xs[(r0 + i) * KC + ((kb ^ i) << 2)];
#pragma unroll
            for (int kk = 0; kk < 4; ++kk) {
                float4 wa = *(const float4*)&Ws[(k + kk) * C + c0];
                float4 wb;
                if constexpr (CPT == 8)
                    wb = *(const float4*)&Ws[(k + kk) * C + c0 + 4];
#pragma unroll
                for (int i = 0; i < 4; ++i) {
                    float xk = ((const float*)&xv[i])[kk];
                    acc[i][0] = fmaf(xk, wa.x, acc[i][0]);
                    acc[i][1] = fmaf(xk, wa.y, acc[i][1]);
                    acc[i][2] = fmaf(xk, wa.z, acc[i][2]);
                    acc[i][3] = fmaf(xk, wa.w, acc[i][3]);
                    if constexpr (CPT == 8) {
                        acc[i][4] = fmaf(xk, wb.x, acc[i][4]);
                        acc[i][5] = fmaf(xk, wb.y, acc[i][5]);
                        acc[i][6] = fmaf(xk, wb.z, acc[i][6]);
                        acc[i][7] = fmaf(xk, wb.w, acc[i][7]);
                    }
                }
            }
        }
    }

#pragma unroll
    for (int i = 0; i < 4; ++i) {
        int row = base + r0 + i;
        if (row < n) {
            *(float4*)(Y + (size_t)row * C + c0) =
                make_float4(acc[i][0], acc[i][1], acc[i][2], acc[i][3]);
            if constexpr (CPT == 8)
                *(float4*)(Y + (size_t)row * C + c0 + 4) =
                    make_float4(acc[i][4], acc[i][5], acc[i][6], acc[i][7]);
        }
    }
}

// ---------------- CSR gather (unroll-4 for memory-level parallelism) ----------------

__global__ __launch_bounds__(TPB) void k_gather64(const float* __restrict__ HW,
                                                  const int* __restrict__ off,
                                                  const int* __restrict__ srcs,
                                                  const float* __restrict__ wnorm,
                                                  const float* __restrict__ dis,
                                                  const float* __restrict__ b,
                                                  float* __restrict__ Y, int n) {
    int node = (blockIdx.x * blockDim.x + threadIdx.x) >> 5;
    int l = threadIdx.x & 31;
    if (node >= n) return;
    const float2* HW2 = (const float2*)HW;
    float dd = dis[node];
    float2 hv = HW2[node * 32 + l];
    float2 bb = ((const float2*)b)[l];
    float a0x = fmaf(dd * dd, hv.x, bb.x);
    float a0y = fmaf(dd * dd, hv.y, bb.y);
    float a1x = 0.f, a1y = 0.f, a2x = 0.f, a2y = 0.f, a3x = 0.f, a3y = 0.f;
    int j = off[node], end = off[node + 1];
    for (; j + 3 < end; j += 4) {
        int s0 = srcs[j], s1 = srcs[j + 1], s2 = srcs[j + 2], s3 = srcs[j + 3];
        float w0 = wnorm[j], w1 = wnorm[j + 1], w2 = wnorm[j + 2], w3 = wnorm[j + 3];
        float2 v0 = HW2[s0 * 32 + l];
        float2 v1 = HW2[s1 * 32 + l];
        float2 v2 = HW2[s2 * 32 + l];
        float2 v3 = HW2[s3 * 32 + l];
        a0x = fmaf(w0, v0.x, a0x); a0y = fmaf(w0, v0.y, a0y);
        a1x = fmaf(w1, v1.x, a1x); a1y = fmaf(w1, v1.y, a1y);
        a2x = fmaf(w2, v2.x, a2x); a2y = fmaf(w2, v2.y, a2y);
        a3x = fmaf(w3, v3.x, a3x); a3y = fmaf(w3, v3.y, a3y);
    }
    for (; j < end; ++j) {
        int s0 = srcs[j];
        float w0 = wnorm[j];
        float2 v0 = HW2[s0 * 32 + l];
        a0x = fmaf(w0, v0.x, a0x); a0y = fmaf(w0, v0.y, a0y);
    }
    float2 o;
    o.x = (a0x + a1x) + (a2x + a3x);
    o.y = (a0y + a1y) + (a2y + a3y);
    ((float2*)Y)[node * 32 + l] = o;
}

__global__ __launch_bounds__(TPB) void k_gather32(const float* __restrict__ HW,
                                                  const int* __restrict__ off,
                                                  const int* __restrict__ srcs,
                                                  const float* __restrict__ wnorm,
                                                  const float* __restrict__ dis,
                                                  const float* __restrict__ b,
                                                  float* __restrict__ Y, int n) {
    int node = (blockIdx.x * blockDim.x + threadIdx.x) >> 5;
    int c = threadIdx.x & 31;
    if (node >= n) return;
    float dd = dis[node];
    float a0 = fmaf(dd * dd, HW[node * 32 + c], b[c]);
    float a1 = 0.f, a2 = 0.f, a3 = 0.f;
    int j = off[node], end = off[node + 1];
    for (; j + 3 < end; j += 4) {
        int s0 = srcs[j], s1 = srcs[j + 1], s2 = srcs[j + 2], s3 = srcs[j + 3];
        float w0 = wnorm[j], w1 = wnorm[j + 1], w2 = wnorm[j + 2], w3 = wnorm[j + 3];
        a0 = fmaf(w0, HW[s0 * 32 + c], a0);
        a1 = fmaf(w1, HW[s1 * 32 + c], a1);
        a2 = fmaf(w2, HW[s2 * 32 + c], a2);
        a3 = fmaf(w3, HW[s3 * 32 + c], a3);
    }
    for (; j < end; ++j)
        a0 = fmaf(wnorm[j], HW[srcs[j] * 32 + c], a0);
    Y[node * 32 + c] = (a0 + a1) + (a2 + a3);
}

// ---------------- launch ----------------

extern "C" void kernel_launch(void* const* d_in, const int* in_sizes, int n_in,
                              void* d_out, int out_size, void* d_ws, size_t ws_size,
                              hipStream_t stream) {
    const float* x  = (const float*)d_in[0];
    const int*   ei = (const int*)d_in[1];
    const float* ew = (const float*)d_in[2];
    const float* W1 = (const float*)d_in[3];
    const float* b1 = (const float*)d_in[4];
    const float* W2 = (const float*)d_in[5];
    const float* b2 = (const float*)d_in[6];
    const float* W3 = (const float*)d_in[7];
    const float* b3 = (const float*)d_in[8];
    float* out = (float*)d_out;

    const int IN_C = 128, HID_C = 64;
    const int N = in_sizes[0] / IN_C;   // 100000 (< 2^17, required by packing)
    const int E = in_sizes[2];          // 1600000

    const int* src = ei;       // edge_index[0] = row (gather source)
    const int* dst = ei + E;   // edge_index[1] = col (destination)

    const int NB   = (N + BKT - 1) / BKT;        // 196 buckets (<=256 required)
    const int NBLK = (E + CH - 1) / CH;          // 391 chunk-blocks
    const int LM   = NB * NBLK;                  // count-matrix size

    // ---- workspace layout ----
    char* w = (char*)d_ws;
    float* dis   = (float*)w;                 w += sizeof(float) * N;
    int*   off   = (int*)w;                   w += sizeof(int) * (N + 1);
    int*   bkst  = (int*)w;                   w += sizeof(int) * (NB + 1);
    int*   bsum  = (int*)w;                   w += sizeof(int) * 64;
    int*   srcs  = (int*)w;                   w += sizeof(int) * E;
    float* wnorm = (float*)w;                 w += sizeof(float) * E;
    // transient region: [M | barr] overlapped later by [A | B]
    char* w2 = (char*)(((size_t)w + 15) & ~(size_t)15);
    int*  M    = (int*)w2;
    int2* barr = (int2*)(((size_t)(M + LM) + 15) & ~(size_t)15);   // E int2
    float* A   = (float*)w2;                                       // N*64
    float* B   = A + (size_t)N * HID_C;                            // N*64

    const int nScanM = (LM + SC_TPB * SC_ITEMS - 1) / (SC_TPB * SC_ITEMS);  // 38 <= 64

    // ---- build CSR + normalization (no global atomics) ----
    k_bucket_count<<<NBLK, 256, 0, stream>>>(dst, M, E, NB, NBLK);
    k_scan_blocks<<<nScanM, SC_TPB, 0, stream>>>(M, bsum, LM);
    k_scan_bsum<<<1, 64, 0, stream>>>(bsum, nScanM, off + N, E);   // also off[N] = E
    k_scan_final<<<nScanM, SC_TPB, 0, stream>>>(M, bsum, M, LM);   // in-place scan
    k_bucket_start<<<(NB + 256) / 256, 256, 0, stream>>>(M, bkst, NB, NBLK, E);
    k_bucket_scatter<<<NBLK, 256, 0, stream>>>(src, dst, ew, M, barr, E, NB, NBLK);
    k_csr_build<<<NB, 256, 0, stream>>>(barr, bkst, dis, off, srcs, wnorm, N);
    k_wnorm<<<(E + 255) / 256, 256, 0, stream>>>(srcs, wnorm, dis, E);

    const int nTiles = (N + 127) / 128;
    const int gHalf = (N * 32 + TPB - 1) / TPB;  // half-wave per node

    // ---- layer 1 ----
    k_gemm<128, 64, false><<<nTiles, 256, 0, stream>>>(x, W1, A, N);
    k_gather64<<<gHalf, TPB, 0, stream>>>(A, off, srcs, wnorm, dis, b1, B, N);

    // ---- layer 2 ----
    k_gemm<64, 64, true><<<nTiles, 256, 0, stream>>>(B, W2, A, N);
    k_gather64<<<gHalf, TPB, 0, stream>>>(A, off, srcs, wnorm, dis, b2, B, N);

    // ---- layer 3 ----
    k_gemm<64, 32, true><<<nTiles, 256, 0, stream>>>(B, W3, A, N);
    k_gather32<<<gHalf, TPB, 0, stream>>>(A, off, srcs, wnorm, dis, b3, out, N);
}